// Round 6
// baseline (41.542 us; speedup 1.0000x reference)
//
#include <hip/hip_runtime.h>
#include <hip/hip_fp16.h>

// CoarseWarp via fp16 channel-BLOCKED gather:
//   K1: P16[(b*4+g4)][py][px][16ch] = (fp16) reflect-pad(ref), g4 = 16-ch group
//   K2: out[b][c][y][x] = sum_{i,j} (f32)P16[(b,g4)][i+sy][j+sx][c%16]
// The 8 (b,g4) combos are pinned to the 8 XCDs via blockIdx&7 (round-robin
// dispatch): per-XCD gather footprint = 2.1 MB < 4 MB L2 -> gathers L2-hit
// after compulsory L3 fills. Lane = (pixel, 8-ch half): 9 uint4 in flight.
// Accumulation f32, same i,j order; masked FMA bit-exact vs skip.

#define B_   2
#define C_   64
#define HR_  254
#define WR_  254
#define HO_  256
#define WO_  256
#define L_   (HR_ * WR_)
#define PPLANE_ ((size_t)HO_ * WO_ * 16)   // halfs per (b,g4) plane = 1,048,576

// ---------------- Kernel 1: transpose + reflect-pad to blocked fp16 ----------
// Block = (b, py, 64-px x-quarter). Coalesced read, fp16 LDS, blocked write.
__global__ __launch_bounds__(256) void pad_transpose_b16(
    const float* __restrict__ ref, _Float16* __restrict__ P)
{
    __shared__ unsigned short srow[C_][66];

    unsigned bid  = blockIdx.x;          // [0, 2048)
    unsigned b    = bid >> 10;
    unsigned rest = bid & 1023u;
    unsigned py   = rest >> 2;
    unsigned x0   = (rest & 3u) * 64u;
    int ry = (py == 0) ? 1 : ((py == HO_ - 1) ? HR_ - 2 : (int)py - 1);

    const float* rrow = ref + ((size_t)b * C_) * (HR_ * WR_) + (size_t)ry * WR_;
    unsigned tid = threadIdx.x;

    #pragma unroll
    for (unsigned k = 0; k < 16; ++k) {
        unsigned e = k * 256u + tid;
        unsigned c = e >> 6, u = e & 63u;
        unsigned px = x0 + u;
        int rx = (px == 0) ? 1 : ((px == WO_ - 1) ? WR_ - 2 : (int)px - 1);
        float v = __builtin_nontemporal_load(&rrow[(size_t)c * (HR_ * WR_) + rx]);
        _Float16 h = (_Float16)v;
        srow[c][u] = __builtin_bit_cast(unsigned short, h);
    }
    __syncthreads();

    // Write blocked planes: per g4, 64 px x 16 ch; u32 = packed channel pair.
    #pragma unroll
    for (unsigned it = 0; it < 8; ++it) {
        unsigned w   = it * 256u + tid;      // [0, 2048)
        unsigned g4  = w >> 9;               // [0,4)
        unsigned rem = w & 511u;
        unsigned pxl = rem >> 3;             // [0,64)
        unsigned cp  = rem & 7u;             // channel pair within group
        unsigned c0  = g4 * 16u + cp * 2u;
        unsigned pk  = (unsigned)srow[c0][pxl]
                     | ((unsigned)srow[c0 + 1][pxl] << 16);
        _Float16* pg = P + ((size_t)(b * 4u + g4) * PPLANE_
                            + ((size_t)py * WO_ + x0 + pxl) * 16u + cp * 2u);
        *reinterpret_cast<unsigned*>(pg) = pk;
    }
}

// ---------------- Kernel 2: L2-resident blocked gather + fold ----------------
// grid 4096 = 8 (b,g4) combos x 512 (y, x-half). blockIdx&7 pins combo->XCD.
// Block 256 thr = 4 waves x 32 px = 128 px of one y-row, 16 channels.
// lane = (pq in [0,32) pixel, h in [0,2) 8-ch half); 9 uint4 loads in flight.
__global__ __launch_bounds__(256) void warp_gather5_kernel(
    const _Float16* __restrict__ P,
    const int*      __restrict__ index_map,
    float*          __restrict__ out)
{
    __shared__ unsigned sbase[3][132];    // rows y-2..y, cols x0-2 .. x0+127

    unsigned bid   = blockIdx.x;          // [0, 4096)
    unsigned combo = bid & 7u;            // -> XCD
    unsigned inner = bid >> 3;            // [0, 512)
    unsigned b     = combo >> 2;
    unsigned g4    = combo & 3u;
    unsigned y     = inner >> 1;
    unsigned x0    = (inner & 1u) * 128u;
    unsigned tid   = threadIdx.x;

    const int* imb = index_map + (size_t)b * L_;
    for (unsigned e = tid; e < 3 * 130; e += 256) {
        unsigned r    = e / 130;          // row y-2+r  (r = 2-i)
        unsigned ccol = e - r * 130;
        int ly = (int)y - 2 + (int)r;
        int lx = (int)(x0 + ccol) - 2;
        unsigned v = 0xFFFFFFFFu;
        if (ly >= 0 && ly < HR_ && lx >= 0 && lx < WR_) {
            unsigned src = (unsigned)imb[ly * WR_ + lx];
            unsigned sy  = src / WR_;
            unsigned sx  = src - sy * WR_;
            v = (sy * (unsigned)WO_ + sx) * 16u;   // half-elem offset in plane
        }
        sbase[r][ccol] = v;
    }
    __syncthreads();

    unsigned wv   = tid >> 6;
    unsigned lane = tid & 63u;
    unsigned pq   = lane >> 1;            // pixel sub-index [0,32)
    unsigned h    = lane & 1u;            // channels g4*16 + 8h .. +7
    unsigned pxl  = wv * 32u + pq;        // local pixel [0,128)
    const _Float16* Pp = P + (size_t)combo * PPLANE_;

    uint4 raw[9];
    float msk[9];
    #pragma unroll
    for (int k = 0; k < 9; ++k) {
        int i = k / 3, j = k % 3;
        unsigned v = sbase[2 - i][pxl + 2u - (unsigned)j];
        bool valid = (v != 0xFFFFFFFFu);
        unsigned off = (valid ? v : 0u)
                     + (unsigned)((i * WO_ + j) * 16) + h * 8u;
        msk[k] = valid ? 1.0f : 0.0f;
        raw[k] = *reinterpret_cast<const uint4*>(Pp + off);
    }

    float acc[8] = {0.f, 0.f, 0.f, 0.f, 0.f, 0.f, 0.f, 0.f};
    #pragma unroll
    for (int k = 0; k < 9; ++k) {
        union { uint4 u; _Float16 hh[8]; } cv;
        cv.u = raw[k];
        #pragma unroll
        for (int m = 0; m < 8; ++m) {
            acc[m] = fmaf((float)cv.hh[m], msk[k], acc[m]);
        }
    }

    // Direct nt stores: per m, half-wave writes 32 consecutive floats (128 B).
    float* ob = out + ((size_t)b * C_) * (HO_ * WO_) + (size_t)y * WO_ + x0;
    #pragma unroll
    for (int m = 0; m < 8; ++m) {
        unsigned ch = g4 * 16u + h * 8u + (unsigned)m;
        __builtin_nontemporal_store(acc[m],
            ob + (size_t)ch * (HO_ * WO_) + pxl);
    }
}

extern "C" void kernel_launch(void* const* d_in, const int* in_sizes, int n_in,
                              void* d_out, int out_size, void* d_ws, size_t ws_size,
                              hipStream_t stream) {
    const float* ref       = (const float*)d_in[1];
    const int*   index_map = (const int*)d_in[2];
    float*       out       = (float*)d_out;

    _Float16* P = (_Float16*)d_ws;   // fully overwritten before use
    pad_transpose_b16<<<dim3(B_ * HO_ * 4), dim3(256), 0, stream>>>(ref, P);
    warp_gather5_kernel<<<dim3(B_ * HO_ * 8), dim3(256), 0, stream>>>(P, index_map, out);
}

// Round 7
// 40.623 us; speedup vs baseline: 1.0226x; 1.0226x over previous
//
#include <hip/hip_runtime.h>
#include <hip/hip_fp16.h>

// CoarseWarp via fp16 32-channel-blocked gather:
//   K1: P32[(b*2+half)][py][px][32ch] = (fp16) reflect-pad(ref)
//   K2: out[b][c][y][x] = sum_{i,j} (f32)P32[(b,half)][i+sy][j+sx][c%32]
// Tap = 32ch fp16 = 64 B = exactly ONE cache line = one TA request (round 5
// had 128 B taps = same line count, 2 lines/request; round 6's 32 B taps
// quadrupled requests and regressed). Per-XCD gather footprint = 4.2 MB
// (~ one XCD L2): combos (b,half) pinned via blockIdx&7 (slots k, k+4 take
// the two y-halves). Accumulation f32, same i,j order; masked FMA bit-exact.

#define B_   2
#define C_   64
#define HR_  254
#define WR_  254
#define HO_  256
#define WO_  256
#define L_   (HR_ * WR_)
#define PPLANE32_ ((size_t)HO_ * WO_ * 32)   // halfs per (b,half) plane (4.2 MB)

// ---------------- Kernel 1: transpose + reflect-pad to blocked fp16 ----------
// Block = (b, py, 64-px x-quarter). Coalesced read, fp16 LDS, blocked write:
// 16 lanes = one pixel's 32 ch = 64 B contiguous.
__global__ __launch_bounds__(256) void pad_transpose_b32(
    const float* __restrict__ ref, _Float16* __restrict__ P)
{
    __shared__ unsigned short srow[C_][66];

    unsigned bid  = blockIdx.x;          // [0, 2048)
    unsigned b    = bid >> 10;
    unsigned rest = bid & 1023u;
    unsigned py   = rest >> 2;
    unsigned x0   = (rest & 3u) * 64u;
    int ry = (py == 0) ? 1 : ((py == HO_ - 1) ? HR_ - 2 : (int)py - 1);

    const float* rrow = ref + ((size_t)b * C_) * (HR_ * WR_) + (size_t)ry * WR_;
    unsigned tid = threadIdx.x;

    #pragma unroll
    for (unsigned k = 0; k < 16; ++k) {
        unsigned e = k * 256u + tid;
        unsigned c = e >> 6, u = e & 63u;
        unsigned px = x0 + u;
        int rx = (px == 0) ? 1 : ((px == WO_ - 1) ? WR_ - 2 : (int)px - 1);
        float v = __builtin_nontemporal_load(&rrow[(size_t)c * (HR_ * WR_) + rx]);
        _Float16 h = (_Float16)v;
        srow[c][u] = __builtin_bit_cast(unsigned short, h);
    }
    __syncthreads();

    // 64 px x 64 ch = 2048 packed u32; half = channel group of 32.
    #pragma unroll
    for (unsigned it = 0; it < 8; ++it) {
        unsigned w    = it * 256u + tid;     // [0, 2048)
        unsigned half = w >> 10;             // [0,2)
        unsigned rem  = w & 1023u;
        unsigned pxl  = rem >> 4;            // [0,64)
        unsigned cp   = rem & 15u;           // ch pair within 32-ch group
        unsigned c0   = half * 32u + cp * 2u;
        unsigned pk   = (unsigned)srow[c0][pxl]
                      | ((unsigned)srow[c0 + 1][pxl] << 16);
        _Float16* pg = P + ((size_t)(b * 2u + half) * PPLANE32_
                            + ((size_t)py * WO_ + x0 + pxl) * 32u + cp * 2u);
        *reinterpret_cast<unsigned*>(pg) = pk;
    }
}

// ---------------- Kernel 2: L2-resident 64B-tap gather + fold ----------------
// grid 4096 = 8 slots x 512. slot = bid&7 -> XCD; combo (b,half) = slot&3,
// y-half = slot>>2. Block = 64 px of one y row, 32 channels.
// lane = (cg in [0,4) 8-ch group, pq in [0,16) pixel); 9 uint4 in flight;
// each tap = 64 B = 1 line = 1 request (4 lanes by address).
__global__ __launch_bounds__(256) void warp_gather6_kernel(
    const _Float16* __restrict__ P,
    const int*      __restrict__ index_map,
    float*          __restrict__ out)
{
    __shared__ unsigned sbase[3][66];     // rows y-2..y, cols x0-2 .. x0+63

    unsigned bid   = blockIdx.x;          // [0, 4096)
    unsigned slot  = bid & 7u;
    unsigned inner = bid >> 3;            // [0, 512)
    unsigned b     = (slot >> 1) & 1u;
    unsigned half  = slot & 1u;
    unsigned yr    = slot >> 2;           // y-half [0,2)
    unsigned y     = yr * 128u + (inner >> 2);
    unsigned x0    = (inner & 3u) * 64u;
    unsigned tid   = threadIdx.x;

    const int* imb = index_map + (size_t)b * L_;
    if (tid < 3 * 66) {
        unsigned r    = tid / 66;         // row y-2+r  (r = 2-i)
        unsigned ccol = tid - r * 66;
        int ly = (int)y - 2 + (int)r;
        int lx = (int)(x0 + ccol) - 2;
        unsigned v = 0xFFFFFFFFu;
        if (ly >= 0 && ly < HR_ && lx >= 0 && lx < WR_) {
            unsigned src = (unsigned)imb[ly * WR_ + lx];
            unsigned sy  = src / WR_;
            unsigned sx  = src - sy * WR_;
            v = (sy * (unsigned)WO_ + sx) * 32u;   // half-elem offset in plane
        }
        sbase[r][ccol] = v;
    }
    __syncthreads();

    unsigned wv   = tid >> 6;
    unsigned lane = tid & 63u;
    unsigned pq   = lane & 15u;           // pixel sub-index [0,16)
    unsigned cg   = lane >> 4;            // 8-ch group [0,4)
    unsigned pxl  = wv * 16u + pq;        // local pixel [0,64)
    const _Float16* Pp = P + (size_t)(b * 2u + half) * PPLANE32_;

    uint4 raw[9];
    float msk[9];
    #pragma unroll
    for (int k = 0; k < 9; ++k) {
        int i = k / 3, j = k % 3;
        unsigned v = sbase[2 - i][pxl + 2u - (unsigned)j];
        bool valid = (v != 0xFFFFFFFFu);
        unsigned off = (valid ? v : 0u)
                     + (unsigned)((i * WO_ + j) * 32) + cg * 8u;
        msk[k] = valid ? 1.0f : 0.0f;
        raw[k] = *reinterpret_cast<const uint4*>(Pp + off);
    }

    float acc[8] = {0.f, 0.f, 0.f, 0.f, 0.f, 0.f, 0.f, 0.f};
    #pragma unroll
    for (int k = 0; k < 9; ++k) {
        union { uint4 u; _Float16 hh[8]; } cv;
        cv.u = raw[k];
        #pragma unroll
        for (int m = 0; m < 8; ++m) {
            acc[m] = fmaf((float)cv.hh[m], msk[k], acc[m]);
        }
    }

    // Direct nt stores: per m, the 16 lanes of each cg form one 64B line.
    float* ob = out + ((size_t)b * C_) * (HO_ * WO_) + (size_t)y * WO_ + x0;
    #pragma unroll
    for (int m = 0; m < 8; ++m) {
        unsigned ch = half * 32u + cg * 8u + (unsigned)m;
        __builtin_nontemporal_store(acc[m],
            ob + (size_t)ch * (HO_ * WO_) + pxl);
    }
}

extern "C" void kernel_launch(void* const* d_in, const int* in_sizes, int n_in,
                              void* d_out, int out_size, void* d_ws, size_t ws_size,
                              hipStream_t stream) {
    const float* ref       = (const float*)d_in[1];
    const int*   index_map = (const int*)d_in[2];
    float*       out       = (float*)d_out;

    _Float16* P = (_Float16*)d_ws;   // fully overwritten before use
    pad_transpose_b32<<<dim3(B_ * HO_ * 4), dim3(256), 0, stream>>>(ref, P);
    warp_gather6_kernel<<<dim3(B_ * HO_ * 8), dim3(256), 0, stream>>>(P, index_map, out);
}